// Round 12
// baseline (1255.004 us; speedup 1.0000x reference)
//
#include <hip/hip_runtime.h>
#include <hip/hip_bf16.h>
#include <hip/hip_cooperative_groups.h>
namespace cg = cooperative_groups;

#define NN 100000
#define NE 1600000
#define NEG_SLOPE 0.2f
#define GEPS 1e-16f
#define WSHIFT 4.0f   // global exp shift: w = exp(alpha-4), softmax-invariant, keeps f16 in range

// ---- atomic-free CSR-build geometry ----
#define HB 64              // edge chunks (deterministic: chunk = e / EB)
#define EB (NE / HB)       // 25000 edges per chunk (multiple of 4)
#define HPASS 4            // node-range passes per chunk
#define HBIN 25000         // bins per pass (4*25000 = NN exactly)
#define HBW (HBIN / 2)     // packed 2x16-bit counters per LDS word -> 50 KB LDS
#define CAPS ((size_t)(NE + 8 * NN))   // max padded CSR slots = 2.4M

// packet .y layout: bits[0:17]=src, bits[17:32]=ez15 (f16>>1, sign+exp+9mant)
#define SRCMASK 0x1FFFFu

// merged hist+gemm grid split
#define HIST_BLKS (HB * HPASS)             // 256
#define GEMM_BLKS ((NN + 127) / 128)       // 782

// tail phase unit counts
#define EDGE_BLKS ((NE / 4 + 255) / 256)   // 1563 edge units
#define FILL_BLKS ((NN + 255) / 256)       // 391 fill units
#define SCAT_UNITS (EDGE_BLKS + FILL_BLKS) // 1954
#define NB_DEG    ((NN + 255) / 256)       // 391
#define NB_SCAN3  ((NN + 1023) / 1024)     // 98
#define AGG1_UNITS ((NN + 3) / 4)          // 25000
#define AGG2_UNITS ((NN + 15) / 16)        // 6250
#define NUM_CU 256

typedef __attribute__((ext_vector_type(8))) short short8;
typedef __attribute__((ext_vector_type(4))) float f32x4;
typedef __attribute__((ext_vector_type(2))) float f32x2;
typedef __attribute__((ext_vector_type(2))) _Float16 h2v;

// fp32 -> bf16 round-to-nearest-even (MFMA staging only)
__device__ __forceinline__ unsigned short f2b(float f) {
  unsigned u = __float_as_uint(f);
  u += 0x7fffu + ((u >> 16) & 1u);
  return (unsigned short)(u >> 16);
}
// fp32 -> f16 (h1 storage: f16 has 11-bit mantissa, better than bf16 for |h|<8)
__device__ __forceinline__ unsigned short f2h(float f) {
  _Float16 h = (_Float16)f;
  return __builtin_bit_cast(unsigned short, h);
}
__device__ __forceinline__ float h2f(unsigned short u) {
  return (float)__builtin_bit_cast(_Float16, u);
}
// pack two fp32 into f16x2 (lo, hi)
__device__ __forceinline__ unsigned pkh2(float lo, float hi) {
  return (unsigned)f2h(lo) | ((unsigned)f2h(hi) << 16);
}
__device__ __forceinline__ float dot2h(unsigned a, unsigned b, float c) {
  return __builtin_amdgcn_fdot2(__builtin_bit_cast(h2v, a), __builtin_bit_cast(h2v, b), c, false);
}
__device__ __forceinline__ unsigned permb(unsigned s0, unsigned s1, int sel) {
  return __builtin_amdgcn_perm(s0, s1, sel);
}
// pack (src, ez) into the packet .y word: 17-bit src | 15-bit truncated f16 ez
__device__ __forceinline__ unsigned pkSE(int src, float ez) {
  return (unsigned)src | ((unsigned)(f2h(ez) >> 1) << 17);
}
__device__ __forceinline__ float unpkEZ(unsigned y) {
  return h2f((unsigned short)((y >> 17) << 1));
}
// non-temporal loads for read-once streams (keeps h1b/nd hot in L2)
__device__ __forceinline__ float4 ntld4(const float4* p) {
  f32x4 v = __builtin_nontemporal_load((const f32x4*)p);
  float4 r; r.x = v.x; r.y = v.y; r.z = v.z; r.w = v.w; return r;
}
__device__ __forceinline__ float2 ntld2(const float2* p) {
  f32x2 v = __builtin_nontemporal_load((const f32x2*)p);
  float2 r; r.x = v.x; r.y = v.y; return r;
}
#define HSEL_LO 0x05040100   // (s1.lo16, s0.lo16)
#define HSEL_HI 0x07060302   // (s1.hi16, s0.hi16)
#define ONE2    0x3C003C00u  // f16 (1.0, 1.0)
#define EZPAD   (-60000.0f)  // pad ez: f16-representable, exp(leaky(.)) == 0

// padded segment length: (deg+1) rounded up to multiple of 8
__device__ __forceinline__ int padlen(int d) { return (d + 8) & ~7; }

// ---------- prep: q (edge-att vectors) + pq[k] = (W1@as1, W1@ad1) per head ----------
__global__ void k_prep(const float* __restrict__ We1, const float* __restrict__ ae1,
                       const float* __restrict__ We2, const float* __restrict__ ae2,
                       const float* __restrict__ W1, const float* __restrict__ as1,
                       const float* __restrict__ ad1,
                       float* __restrict__ q, float4* __restrict__ pq) {
  int t = threadIdx.x;
  if (t < 6) {
    int d = t >> 1, hh = t & 1;
    float s = 0.f;
    for (int c = 0; c < 64; ++c) s += We1[d * 128 + hh * 64 + c] * ae1[hh * 64 + c];
    q[t] = s;
  } else if (t < 9) {
    int d = t - 6;
    q[8 + d] = We2[d * 2 + 0] * ae2[0] + We2[d * 2 + 1] * ae2[1];
  }
  if (t < 128) {
    float s0 = 0.f, s1 = 0.f, d0 = 0.f, d1 = 0.f;
    for (int c = 0; c < 64; ++c) {
      float w0 = W1[t * 128 + c], w1 = W1[t * 128 + 64 + c];
      s0 += w0 * as1[c];      s1 += w1 * as1[64 + c];
      d0 += w0 * ad1[c];      d1 += w1 * ad1[64 + c];
    }
    pq[t] = make_float4(s0, s1, d0, d1);
  }
}

// ---------- MERGED: hist (blocks [0,256)) + layer1 GEMM (blocks [256,256+782)) ----
__global__ __launch_bounds__(512, 4) void k_gh(
    const int* __restrict__ ei, unsigned short* __restrict__ off16,
    unsigned short* __restrict__ rank,
    const float* __restrict__ x, const float* __restrict__ W,
    const float4* __restrict__ pq, unsigned short* __restrict__ h1b,
    float* __restrict__ a1s, float* __restrict__ a1d) {
  __shared__ union SM {
    struct { unsigned short xa[128 * 128]; unsigned short wt[128 * 128]; } g;
    unsigned cnt[HBW];
  } sm;
  int t = threadIdx.x;

  if (blockIdx.x < HIST_BLKS) {
    int b = blockIdx.x >> 2;               // edge chunk
    int pass = blockIdx.x & 3;             // node range
    int base = pass * HBIN;
    for (int i = t; i < HBW; i += 512) sm.cnt[i] = 0;
    __syncthreads();
    const int* dsts = &ei[NE + b * EB];
    for (int i = t * 4; i < EB; i += 2048) {
      int4 d = *(const int4*)&dsts[i];
      int dv[4] = {d.x, d.y, d.z, d.w};
#pragma unroll
      for (int j = 0; j < 4; ++j) {
        int rel = dv[j] - base;
        if ((unsigned)rel < (unsigned)HBIN) {
          unsigned sh = (unsigned)(rel & 1) << 4;
          unsigned old = atomicAdd(&sm.cnt[rel >> 1], 1u << sh);
          rank[b * EB + i + j] = (unsigned short)((old >> sh) & 0xffffu);
        }
      }
    }
    __syncthreads();
    unsigned short* dp = &off16[(size_t)b * NN + base];
    for (int i = t; i < HBW; i += 512) *(unsigned*)&dp[i * 2] = sm.cnt[i];
    return;
  }

  unsigned short* xa = sm.g.xa;
  unsigned short* wt = sm.g.wt;
  int row0 = (int)(blockIdx.x - HIST_BLKS) * 128;

  {
    int kr = t >> 2, n0 = (t & 3) * 32;
    const float* wp = &W[kr * 128 + n0];
    int cb = kr >> 3, klo = kr & 7;
#pragma unroll
    for (int j = 0; j < 8; ++j) {
      float4 v = *(const float4*)&wp[j * 4];
      int n = n0 + j * 4;
      wt[(n + 0) * 128 + ((cb ^ ((n + 0) & 15)) * 8) + klo] = f2b(v.x);
      wt[(n + 1) * 128 + ((cb ^ ((n + 1) & 15)) * 8) + klo] = f2b(v.y);
      wt[(n + 2) * 128 + ((cb ^ ((n + 2) & 15)) * 8) + klo] = f2b(v.z);
      wt[(n + 3) * 128 + ((cb ^ ((n + 3) & 15)) * 8) + klo] = f2b(v.w);
    }
  }
  {
    int lrow = t >> 2, qq = t & 3;
    int grow = row0 + lrow; if (grow >= NN) grow = NN - 1;
    const float* xp = &x[(size_t)grow * 128 + qq * 32];
    const float4* pqp = &pq[qq * 32];
    float ps0 = 0.f, ps1 = 0.f, pd0 = 0.f, pd1 = 0.f;
    int sw = lrow & 15;
#pragma unroll
    for (int j = 0; j < 4; ++j) {
      float4 u = *(const float4*)&xp[j * 8];
      float4 v = *(const float4*)&xp[j * 8 + 4];
      float xs[8] = {u.x, u.y, u.z, u.w, v.x, v.y, v.z, v.w};
      short8 sv;
#pragma unroll
      for (int e = 0; e < 8; ++e) {
        float4 pv = pqp[j * 8 + e];
        ps0 += xs[e] * pv.x; ps1 += xs[e] * pv.y;
        pd0 += xs[e] * pv.z; pd1 += xs[e] * pv.w;
        sv[e] = (short)f2b(xs[e]);
      }
      int c = qq * 4 + j;
      *(short8*)&xa[lrow * 128 + ((c ^ sw) * 8)] = sv;
    }
    ps0 += __shfl_xor(ps0, 1); ps0 += __shfl_xor(ps0, 2);
    ps1 += __shfl_xor(ps1, 1); ps1 += __shfl_xor(ps1, 2);
    pd0 += __shfl_xor(pd0, 1); pd0 += __shfl_xor(pd0, 2);
    pd1 += __shfl_xor(pd1, 1); pd1 += __shfl_xor(pd1, 2);
    if (qq == 0) {
      *(float2*)&a1s[grow * 2] = make_float2(ps0, ps1);
      *(float2*)&a1d[grow * 2] = make_float2(pd0, pd1);
    }
  }
  __syncthreads();

  int lane = t & 63, w = t >> 6;
  int m = lane & 15, quad = lane >> 4;
  int wm = (w & 1) * 64, wn = (w >> 1) * 32;
  f32x4 acc[4][2];
#pragma unroll
  for (int mi = 0; mi < 4; ++mi)
#pragma unroll
    for (int ni = 0; ni < 2; ++ni) acc[mi][ni] = (f32x4)(0.f);

#pragma unroll
  for (int kk = 0; kk < 4; ++kk) {
    int c = kk * 4 + quad;
    int co = (c ^ m) * 8;
    short8 a[4], b[2];
#pragma unroll
    for (int mi = 0; mi < 4; ++mi)
      a[mi] = *(const short8*)&xa[(wm + mi * 16 + m) * 128 + co];
#pragma unroll
    for (int ni = 0; ni < 2; ++ni)
      b[ni] = *(const short8*)&wt[(wn + ni * 16 + m) * 128 + co];
#pragma unroll
    for (int mi = 0; mi < 4; ++mi)
#pragma unroll
      for (int ni = 0; ni < 2; ++ni)
        acc[mi][ni] = __builtin_amdgcn_mfma_f32_16x16x32_bf16(a[mi], b[ni], acc[mi][ni], 0, 0, 0);
  }
#pragma unroll
  for (int mi = 0; mi < 4; ++mi)
#pragma unroll
    for (int r = 0; r < 4; ++r) {
      int grow = row0 + wm + mi * 16 + quad * 4 + r;
      if (grow >= NN) grow = NN - 1;
#pragma unroll
      for (int ni = 0; ni < 2; ++ni)
        h1b[(size_t)grow * 128 + wn + ni * 16 + m] = f2h(acc[mi][ni][r]);
    }
}

// ================= shared phase bodies (used by coop k_tail AND fallback) =========
__device__ __forceinline__ void d_degscan(int u, int t, unsigned short* off16,
                                          int* deg, int* bsum, int* lds) {
  int n = u * 256 + t;
  int run = 0;
  if (n < NN) {
    for (int b = 0; b < HB; ++b) {
      size_t idx = (size_t)b * NN + n;
      int c = off16[idx];
      off16[idx] = (unsigned short)run;   // exclusive offset of chunk b within node n
      run += c;
    }
    deg[n] = run;
  }
  lds[t] = (n < NN) ? padlen(run) : 0;
  __syncthreads();
  for (int o = 128; o > 0; o >>= 1) { if (t < o) lds[t] += lds[t + o]; __syncthreads(); }
  if (t == 0) bsum[u] = lds[0];
  __syncthreads();
}

__device__ __forceinline__ void d_scan3(int u, int t, const int* deg, const int* bsum,
                                        int* rowptr, int* lds) {
  int lim = u * 4;
  int a = 0;
  for (int i = t; i < lim; i += 256) a += bsum[i];
  lds[t] = a; __syncthreads();
  for (int o = 128; o > 0; o >>= 1) { if (t < o) lds[t] += lds[t + o]; __syncthreads(); }
  int bbv = lds[0];
  __syncthreads();
  int base = u * 1024 + t * 4;
  int v[4]; int s = 0;
  for (int j = 0; j < 4; ++j) { int i = base + j; v[j] = (i < NN) ? padlen(deg[i]) : 0; s += v[j]; }
  lds[t] = s; __syncthreads();
  for (int o = 1; o < 256; o <<= 1) {
    int uu = (t >= o) ? lds[t - o] : 0;
    __syncthreads();
    lds[t] += uu;
    __syncthreads();
  }
  int excl = lds[t] - s + bbv;
  for (int j = 0; j < 4; ++j) {
    int i = base + j;
    if (i <= NN) rowptr[i] = excl;
    excl += v[j];
  }
  __syncthreads();
}

__device__ __forceinline__ void d_scat(int u, int t, const int* ei, const float* ef,
                                       const float* a1s, const float* a1d,
                                       const float* q, const int* rowptr,
                                       const int* deg, const unsigned short* rank,
                                       const unsigned short* off16, float2* cpk1) {
  if (u < EDGE_BLKS) {
    int t4 = u * 256 + t;
    if (t4 >= NE / 4) return;
    int e0 = t4 * 4;
    int hb = e0 / EB;                     // all 4 edges in same chunk (EB % 4 == 0)
    const unsigned short* offp = &off16[(size_t)hb * NN];
    int4 ss = *(const int4*)&ei[e0];
    int4 dd = *(const int4*)&ei[NE + e0];
    ushort4 rk = *(const ushort4*)&rank[e0];
    float4 fA = *(const float4*)&ef[e0 * 3];
    float4 fB = *(const float4*)&ef[e0 * 3 + 4];
    float4 fC = *(const float4*)&ef[e0 * 3 + 8];
    float f[4][3] = {{fA.x, fA.y, fA.z}, {fA.w, fB.x, fB.y},
                     {fB.z, fB.w, fC.x}, {fC.y, fC.z, fC.w}};
    int src[4] = {ss.x, ss.y, ss.z, ss.w};
    int dst[4] = {dd.x, dd.y, dd.z, dd.w};
    int rnk[4] = {rk.x, rk.y, rk.z, rk.w};
#pragma unroll
    for (int j = 0; j < 4; ++j) {
      float e0h = f[j][0] * q[0] + f[j][1] * q[2] + f[j][2] * q[4];
      float e1h = f[j][0] * q[1] + f[j][1] * q[3] + f[j][2] * q[5];
      float ez  = f[j][0] * q[8] + f[j][1] * q[9] + f[j][2] * q[10];
      float al0 = a1s[src[j] * 2] + a1d[dst[j] * 2] + e0h;
      float al1 = a1s[src[j] * 2 + 1] + a1d[dst[j] * 2 + 1] + e1h;
      al0 = al0 > 0.f ? al0 : NEG_SLOPE * al0;
      al1 = al1 > 0.f ? al1 : NEG_SLOPE * al1;
      int pos = rowptr[dst[j]] + 1 + (int)offp[dst[j]] + rnk[j];
      cpk1[pos] = make_float2(
          __uint_as_float(pkh2(__expf(al0 - WSHIFT), __expf(al1 - WSHIFT))),
          __uint_as_float(pkSE(src[j], ez)));
    }
  } else {
    int n = (u - EDGE_BLKS) * 256 + t;
    if (n >= NN) return;
    int s0 = rowptr[n];
    int d = deg[n];
    int pl = padlen(d);
    float2 sv = *(const float2*)&a1s[n * 2];
    float2 dv = *(const float2*)&a1d[n * 2];
    float al0 = sv.x + dv.x;
    float al1 = sv.y + dv.y;
    al0 = al0 > 0.f ? al0 : NEG_SLOPE * al0;
    al1 = al1 > 0.f ? al1 : NEG_SLOPE * al1;
    cpk1[s0] = make_float2(
        __uint_as_float(pkh2(__expf(al0 - WSHIFT), __expf(al1 - WSHIFT))),
        __uint_as_float(pkSE(n, 0.f)));       // self-loop at slot 0, ez = 0
    float2 pad = make_float2(0.f, __uint_as_float(pkSE(n, EZPAD)));
    for (int k = 1 + d; k < pl; ++k) cpk1[s0 + k] = pad;
  }
}

__device__ __forceinline__ void d_agg1(int u, int t, const unsigned short* h1b,
                                       const int* rowptr, const float2* cpk1,
                                       const float* b1, const float* W2,
                                       const float* as2, const float* ad2, float4* nd) {
  int n = u * 4 + (t >> 6);
  int lane = t & 63;
  if (n >= NN) return;
  int s0 = rowptr[n], s1 = rowptr[n + 1];
  int g = lane >> 4;
  int lp = lane & 15;
  int wsel = (lp >= 8) ? HSEL_HI : HSEL_LO;
  float acc[8];
#pragma unroll
  for (int j = 0; j < 8; ++j) acc[j] = 0.f;
  float den = 0.f;
  int i = s0;
  for (; i + 16 <= s1; i += 16) {
    const float4* pp = (const float4*)(cpk1 + i + 4 * g);
    float4 p01 = ntld4(pp);       // (wA, yA, wB, yB)
    float4 p23 = ntld4(pp + 1);   // (wC, yC, wD, yD)
    uint4 vA = *((const uint4*)(h1b + ((size_t)(__float_as_uint(p01.y) & SRCMASK) << 7)) + lp);
    uint4 vB = *((const uint4*)(h1b + ((size_t)(__float_as_uint(p01.w) & SRCMASK) << 7)) + lp);
    uint4 vC = *((const uint4*)(h1b + ((size_t)(__float_as_uint(p23.y) & SRCMASK) << 7)) + lp);
    uint4 vD = *((const uint4*)(h1b + ((size_t)(__float_as_uint(p23.w) & SRCMASK) << 7)) + lp);
    unsigned wAB = permb(__float_as_uint(p01.z), __float_as_uint(p01.x), wsel);
    unsigned wCD = permb(__float_as_uint(p23.z), __float_as_uint(p23.x), wsel);
    den = dot2h(wAB, ONE2, den);
    den = dot2h(wCD, ONE2, den);
    acc[0] = dot2h(permb(vB.x, vA.x, HSEL_LO), wAB, acc[0]);
    acc[1] = dot2h(permb(vB.x, vA.x, HSEL_HI), wAB, acc[1]);
    acc[2] = dot2h(permb(vB.y, vA.y, HSEL_LO), wAB, acc[2]);
    acc[3] = dot2h(permb(vB.y, vA.y, HSEL_HI), wAB, acc[3]);
    acc[4] = dot2h(permb(vB.z, vA.z, HSEL_LO), wAB, acc[4]);
    acc[5] = dot2h(permb(vB.z, vA.z, HSEL_HI), wAB, acc[5]);
    acc[6] = dot2h(permb(vB.w, vA.w, HSEL_LO), wAB, acc[6]);
    acc[7] = dot2h(permb(vB.w, vA.w, HSEL_HI), wAB, acc[7]);
    acc[0] = dot2h(permb(vD.x, vC.x, HSEL_LO), wCD, acc[0]);
    acc[1] = dot2h(permb(vD.x, vC.x, HSEL_HI), wCD, acc[1]);
    acc[2] = dot2h(permb(vD.y, vC.y, HSEL_LO), wCD, acc[2]);
    acc[3] = dot2h(permb(vD.y, vC.y, HSEL_HI), wCD, acc[3]);
    acc[4] = dot2h(permb(vD.z, vC.z, HSEL_LO), wCD, acc[4]);
    acc[5] = dot2h(permb(vD.z, vC.z, HSEL_HI), wCD, acc[5]);
    acc[6] = dot2h(permb(vD.w, vC.w, HSEL_LO), wCD, acc[6]);
    acc[7] = dot2h(permb(vD.w, vC.w, HSEL_HI), wCD, acc[7]);
  }
  if (i < s1) {                       // exactly one 8-edge block
    float4 p = ntld4((const float4*)(cpk1 + i + 2 * g));
    uint4 vA = *((const uint4*)(h1b + ((size_t)(__float_as_uint(p.y) & SRCMASK) << 7)) + lp);
    uint4 vB = *((const uint4*)(h1b + ((size_t)(__float_as_uint(p.w) & SRCMASK) << 7)) + lp);
    unsigned wAB = permb(__float_as_uint(p.z), __float_as_uint(p.x), wsel);
    den = dot2h(wAB, ONE2, den);
    acc[0] = dot2h(permb(vB.x, vA.x, HSEL_LO), wAB, acc[0]);
    acc[1] = dot2h(permb(vB.x, vA.x, HSEL_HI), wAB, acc[1]);
    acc[2] = dot2h(permb(vB.y, vA.y, HSEL_LO), wAB, acc[2]);
    acc[3] = dot2h(permb(vB.y, vA.y, HSEL_HI), wAB, acc[3]);
    acc[4] = dot2h(permb(vB.z, vA.z, HSEL_LO), wAB, acc[4]);
    acc[5] = dot2h(permb(vB.z, vA.z, HSEL_HI), wAB, acc[5]);
    acc[6] = dot2h(permb(vB.w, vA.w, HSEL_LO), wAB, acc[6]);
    acc[7] = dot2h(permb(vB.w, vA.w, HSEL_HI), wAB, acc[7]);
  }
#pragma unroll
  for (int o = 16; o <= 32; o <<= 1) {
    den += __shfl_xor(den, o);
#pragma unroll
    for (int j = 0; j < 8; ++j) acc[j] += __shfl_xor(acc[j], o);
  }
  float4 bA = *(const float4*)&b1[lp * 8];
  float4 bB = *(const float4*)&b1[lp * 8 + 4];
  float bbv[8] = {bA.x, bA.y, bA.z, bA.w, bB.x, bB.y, bB.z, bB.w};
  float inv = 1.f / (den + GEPS);
  float r[8];
#pragma unroll
  for (int j = 0; j < 8; ++j) {
    float v = acc[j] * inv + bbv[j];
    r[j] = v > 0.f ? v : __expf(v) - 1.f;   // ELU
  }
  float4 wA = *(const float4*)&W2[lp * 16];
  float4 wB = *(const float4*)&W2[lp * 16 + 4];
  float4 wC = *(const float4*)&W2[lp * 16 + 8];
  float4 wD = *(const float4*)&W2[lp * 16 + 12];
  float p20 = r[0] * wA.x + r[1] * wA.z + r[2] * wB.x + r[3] * wB.z
            + r[4] * wC.x + r[5] * wC.z + r[6] * wD.x + r[7] * wD.z;
  float p21 = r[0] * wA.y + r[1] * wA.w + r[2] * wB.y + r[3] * wB.w
            + r[4] * wC.y + r[5] * wC.w + r[6] * wD.y + r[7] * wD.w;
#pragma unroll
  for (int o = 1; o <= 8; o <<= 1) { p20 += __shfl_xor(p20, o); p21 += __shfl_xor(p21, o); }
  if (lane == 0) {
    float4 v;
    v.x = p20; v.y = p21;
    v.z = p20 * as2[0] + p21 * as2[1];
    v.w = p20 * ad2[0] + p21 * ad2[1];
    nd[n] = v;
  }
}

__device__ __forceinline__ void d_agg2(int u, int t, const int* rowptr,
                                       const float2* cpk1, const float4* nd,
                                       const float* b2, float* out) {
  int wid = u * 4 + (t >> 6);
  int lane = t & 63;
  int g = lane >> 4, lp = lane & 15;
  int n = wid * 4 + g;
  if (n >= NN) return;
  int s0 = rowptr[n], s1 = rowptr[n + 1];
  float adn = nd[n].w;
  float den = 0.f, acc0 = 0.f, acc1 = 0.f;
  for (int i = s0 + lp; i < s1; i += 16) {
    float2 pk = ntld2(&cpk1[i]);
    unsigned y = __float_as_uint(pk.y);
    int s = (int)(y & SRCMASK);
    float ezv = unpkEZ(y);
    float4 ns = nd[s];
    float v = ns.z + adn + ezv;
    v = v > 0.f ? v : NEG_SLOPE * v;
    float p = __expf(v);
    den += p;
    acc0 += p * ns.x;
    acc1 += p * ns.y;
  }
#pragma unroll
  for (int o = 1; o <= 8; o <<= 1) {
    den += __shfl_xor(den, o);
    acc0 += __shfl_xor(acc0, o);
    acc1 += __shfl_xor(acc1, o);
  }
  if (lp == 0) {
    float2 r;
    r.x = acc0 / (den + GEPS) + b2[0];
    r.y = acc1 / (den + GEPS) + b2[1];
    *(float2*)&out[n * 2] = r;
  }
}

// ---------- cooperative tail: all 5 phases with grid.sync between ----------
__global__ __launch_bounds__(256, 8) void k_tail(
    unsigned short* __restrict__ off16, int* __restrict__ deg, int* __restrict__ bsum,
    const int* __restrict__ ei, const float* __restrict__ ef,
    const float* __restrict__ a1s, const float* __restrict__ a1d,
    const float* __restrict__ q, int* __restrict__ rowptr,
    const unsigned short* __restrict__ rank, float2* __restrict__ cpk1,
    const unsigned short* __restrict__ h1b, const float* __restrict__ b1,
    const float* __restrict__ W2, const float* __restrict__ as2,
    const float* __restrict__ ad2, float4* __restrict__ nd,
    const float* __restrict__ b2, float* __restrict__ out) {
  cg::grid_group grid = cg::this_grid();
  __shared__ int lds[256];
  int t = threadIdx.x;

  for (int u = blockIdx.x; u < NB_DEG; u += gridDim.x)
    d_degscan(u, t, off16, deg, bsum, lds);
  __threadfence();
  grid.sync();

  for (int u = blockIdx.x; u < NB_SCAN3; u += gridDim.x)
    d_scan3(u, t, deg, bsum, rowptr, lds);
  __threadfence();
  grid.sync();

  for (int u = blockIdx.x; u < SCAT_UNITS; u += gridDim.x)
    d_scat(u, t, ei, ef, a1s, a1d, q, rowptr, deg, rank, off16, cpk1);
  __threadfence();
  grid.sync();

  for (int u = blockIdx.x; u < AGG1_UNITS; u += gridDim.x)
    d_agg1(u, t, h1b, rowptr, cpk1, b1, W2, as2, ad2, nd);
  __threadfence();
  grid.sync();

  for (int u = blockIdx.x; u < AGG2_UNITS; u += gridDim.x)
    d_agg2(u, t, rowptr, cpk1, nd, b2, out);
}

// ---------- standalone fallbacks (proven round-10 path) ----------
__global__ __launch_bounds__(256) void k_degscan(unsigned short* __restrict__ off16,
                                                 int* __restrict__ deg,
                                                 int* __restrict__ bsum) {
  __shared__ int lds[256];
  d_degscan(blockIdx.x, threadIdx.x, off16, deg, bsum, lds);
}
__global__ __launch_bounds__(256) void k_scan3(const int* __restrict__ deg,
                                               const int* __restrict__ bsum,
                                               int* __restrict__ rowptr) {
  __shared__ int lds[256];
  d_scan3(blockIdx.x, threadIdx.x, deg, bsum, rowptr, lds);
}
__global__ __launch_bounds__(256) void k_scatter(
    const int* __restrict__ ei, const float* __restrict__ ef,
    const float* __restrict__ a1s, const float* __restrict__ a1d,
    const float* __restrict__ q, const int* __restrict__ rowptr,
    const int* __restrict__ deg, const unsigned short* __restrict__ rank,
    const unsigned short* __restrict__ off16, float2* __restrict__ cpk1) {
  d_scat(blockIdx.x, threadIdx.x, ei, ef, a1s, a1d, q, rowptr, deg, rank, off16, cpk1);
}
__global__ __launch_bounds__(256) void k_agg1(
    const unsigned short* __restrict__ h1b, const int* __restrict__ rowptr,
    const float2* __restrict__ cpk1, const float* __restrict__ b1,
    const float* __restrict__ W2, const float* __restrict__ as2,
    const float* __restrict__ ad2, float4* __restrict__ nd) {
  d_agg1(blockIdx.x, threadIdx.x, h1b, rowptr, cpk1, b1, W2, as2, ad2, nd);
}
__global__ __launch_bounds__(256) void k_agg2(
    const int* __restrict__ rowptr, const float2* __restrict__ cpk1,
    const float4* __restrict__ nd, const float* __restrict__ b2,
    float* __restrict__ out) {
  d_agg2(blockIdx.x, threadIdx.x, rowptr, cpk1, nd, b2, out);
}

extern "C" void kernel_launch(void* const* d_in, const int* in_sizes, int n_in,
                              void* d_out, int out_size, void* d_ws, size_t ws_size,
                              hipStream_t stream) {
  (void)in_sizes; (void)n_in; (void)out_size; (void)ws_size;
  const float* x   = (const float*)d_in[0];
  const int*   ei  = (const int*)d_in[1];
  const float* ef  = (const float*)d_in[2];
  const float* W1  = (const float*)d_in[3];
  const float* We1 = (const float*)d_in[4];
  const float* as1 = (const float*)d_in[5];
  const float* ad1 = (const float*)d_in[6];
  const float* ae1 = (const float*)d_in[7];
  const float* b1  = (const float*)d_in[8];
  const float* W2  = (const float*)d_in[9];
  const float* We2 = (const float*)d_in[10];
  const float* as2 = (const float*)d_in[11];
  const float* ad2 = (const float*)d_in[12];
  const float* ae2 = (const float*)d_in[13];
  const float* b2  = (const float*)d_in[14];
  float* out = (float*)d_out;

  char* w = (char*)d_ws;
  auto alloc = [&](size_t bytes) -> char* {
    char* p = w; w += (bytes + 255) & ~(size_t)255; return p;
  };
  unsigned short* h1b = (unsigned short*)alloc((size_t)NN * 128 * 2);  // 25.6 MB (f16)
  float*  a1s    = (float*)alloc((size_t)NN * 2 * 4);
  float*  a1d    = (float*)alloc((size_t)NN * 2 * 4);
  float4* nd     = (float4*)alloc((size_t)NN * 16);
  float*  q      = (float*)alloc(64);
  float4* pq     = (float4*)alloc(128 * 16);
  int*    deg    = (int*)alloc((size_t)NN * 4);
  int*    rowptr = (int*)alloc((size_t)(NN + 1) * 4);
  unsigned short* rank  = (unsigned short*)alloc((size_t)NE * 2);       // 3.2 MB
  unsigned short* off16 = (unsigned short*)alloc((size_t)HB * NN * 2);  // 12.8 MB
  int*    bsum   = (int*)alloc(512 * 4);                                // 391 used
  float2* cpk1   = (float2*)alloc(CAPS * 8);                            // 19.2 MB
  // total ≈ 63 MB (well under round-1's proven 77.6 MB)

  hipLaunchKernelGGL(k_prep, dim3(1), dim3(128), 0, stream,
                     We1, ae1, We2, ae2, W1, as1, ad1, q, pq);
  hipLaunchKernelGGL(k_gh, dim3(HIST_BLKS + GEMM_BLKS), dim3(512), 0, stream,
                     ei, off16, rank, x, W1, pq, h1b, a1s, a1d);

  // cooperative tail with runtime occupancy sizing + checked fallback
  bool coop_ok = false;
  {
    int occ = 0;
    hipError_t e1 = hipOccupancyMaxActiveBlocksPerMultiprocessor(
        &occ, (const void*)k_tail, 256, 0);
    if (e1 == hipSuccess && occ > 0) {
      long long blocks = (long long)occ * NUM_CU;
      if (blocks > SCAT_UNITS) blocks = SCAT_UNITS;   // largest phase unit count
      void* args[] = {(void*)&off16, (void*)&deg, (void*)&bsum, (void*)&ei, (void*)&ef,
                      (void*)&a1s, (void*)&a1d, (void*)&q, (void*)&rowptr, (void*)&rank,
                      (void*)&cpk1, (void*)&h1b, (void*)&b1, (void*)&W2, (void*)&as2,
                      (void*)&ad2, (void*)&nd, (void*)&b2, (void*)&out};
      hipError_t e2 = hipLaunchCooperativeKernel((const void*)k_tail,
                                                 dim3((unsigned)blocks), dim3(256),
                                                 args, 0, stream);
      coop_ok = (e2 == hipSuccess);
    }
  }
  if (!coop_ok) {
    // proven round-10 path
    hipLaunchKernelGGL(k_degscan, dim3(NB_DEG), dim3(256), 0, stream, off16, deg, bsum);
    hipLaunchKernelGGL(k_scan3, dim3(NB_SCAN3), dim3(256), 0, stream, deg, bsum, rowptr);
    hipLaunchKernelGGL(k_scatter, dim3(SCAT_UNITS), dim3(256), 0, stream,
                       ei, ef, a1s, a1d, q, rowptr, deg, rank, off16, cpk1);
    hipLaunchKernelGGL(k_agg1, dim3(AGG1_UNITS), dim3(256), 0, stream,
                       h1b, rowptr, cpk1, b1, W2, as2, ad2, nd);
    hipLaunchKernelGGL(k_agg2, dim3(AGG2_UNITS), dim3(256), 0, stream,
                       rowptr, cpk1, nd, b2, out);
  }
}

// Round 13
// 332.025 us; speedup vs baseline: 3.7799x; 3.7799x over previous
//
#include <hip/hip_runtime.h>
#include <hip/hip_bf16.h>

#define NN 100000
#define NE 1600000
#define NEG_SLOPE 0.2f
#define GEPS 1e-16f
#define WSHIFT 4.0f   // global exp shift: w = exp(alpha-4), softmax-invariant, keeps f16 in range

// ---- atomic-free CSR-build geometry ----
#define HB 64              // edge chunks (deterministic: chunk = e / EB)
#define EB (NE / HB)       // 25000 edges per chunk (multiple of 4)
#define HPASS 4            // node-range passes per chunk
#define HBIN 25000         // bins per pass (4*25000 = NN exactly)
#define HBW (HBIN / 2)     // packed 2x16-bit counters per LDS word -> 50 KB LDS
#define CAPS ((size_t)(NE + 8 * NN))   // max padded CSR slots = 2.4M

// packet .y layout: bits[0:17]=src, bits[17:32]=ez15 (f16>>1, sign+exp+9mant)
#define SRCMASK 0x1FFFFu

// merged hist+gemm grid split
#define HIST_BLKS (HB * HPASS)             // 256
#define GEMM_BLKS ((NN + 127) / 128)       // 782

// scatter grid split: edge blocks then fill blocks (self-loop + pads)
#define EDGE_BLKS ((NE / 4 + 255) / 256)   // 1563
#define FILL_BLKS ((NN + 255) / 256)       // 391
#define NB_DEG    ((NN + 255) / 256)       // 391 degscan blocks (1 node/thread)

typedef __attribute__((ext_vector_type(8))) short short8;
typedef __attribute__((ext_vector_type(4))) float f32x4;
typedef __attribute__((ext_vector_type(2))) float f32x2;
typedef __attribute__((ext_vector_type(2))) _Float16 h2v;

// fp32 -> bf16 round-to-nearest-even (MFMA staging only)
__device__ __forceinline__ unsigned short f2b(float f) {
  unsigned u = __float_as_uint(f);
  u += 0x7fffu + ((u >> 16) & 1u);
  return (unsigned short)(u >> 16);
}
// fp32 -> f16 (h1 storage: f16 has 11-bit mantissa, better than bf16 for |h|<8)
__device__ __forceinline__ unsigned short f2h(float f) {
  _Float16 h = (_Float16)f;
  return __builtin_bit_cast(unsigned short, h);
}
__device__ __forceinline__ float h2f(unsigned short u) {
  return (float)__builtin_bit_cast(_Float16, u);
}
// pack two fp32 into f16x2 (lo, hi)
__device__ __forceinline__ unsigned pkh2(float lo, float hi) {
  return (unsigned)f2h(lo) | ((unsigned)f2h(hi) << 16);
}
__device__ __forceinline__ float dot2h(unsigned a, unsigned b, float c) {
  return __builtin_amdgcn_fdot2(__builtin_bit_cast(h2v, a), __builtin_bit_cast(h2v, b), c, false);
}
__device__ __forceinline__ unsigned permb(unsigned s0, unsigned s1, int sel) {
  return __builtin_amdgcn_perm(s0, s1, sel);
}
// pack (src, ez) into the packet .y word: 17-bit src | 15-bit truncated f16 ez
__device__ __forceinline__ unsigned pkSE(int src, float ez) {
  return (unsigned)src | ((unsigned)(f2h(ez) >> 1) << 17);
}
__device__ __forceinline__ float unpkEZ(unsigned y) {
  return h2f((unsigned short)((y >> 17) << 1));
}
// non-temporal loads for read-once streams (keeps h1b/nd hot in L2)
__device__ __forceinline__ float4 ntld4(const float4* p) {
  f32x4 v = __builtin_nontemporal_load((const f32x4*)p);
  float4 r; r.x = v.x; r.y = v.y; r.z = v.z; r.w = v.w; return r;
}
__device__ __forceinline__ float2 ntld2(const float2* p) {
  f32x2 v = __builtin_nontemporal_load((const f32x2*)p);
  float2 r; r.x = v.x; r.y = v.y; return r;
}
#define HSEL_LO 0x05040100   // (s1.lo16, s0.lo16)
#define HSEL_HI 0x07060302   // (s1.hi16, s0.hi16)
#define ONE2    0x3C003C00u  // f16 (1.0, 1.0)
#define EZPAD   (-60000.0f)  // pad ez: f16-representable, exp(leaky(.)) == 0

// ---------- prep: q (edge-att vectors) + pq[k] = (W1@as1, W1@ad1) per head ----------
__global__ void k_prep(const float* __restrict__ We1, const float* __restrict__ ae1,
                       const float* __restrict__ We2, const float* __restrict__ ae2,
                       const float* __restrict__ W1, const float* __restrict__ as1,
                       const float* __restrict__ ad1,
                       float* __restrict__ q, float4* __restrict__ pq) {
  int t = threadIdx.x;
  if (t < 6) {
    int d = t >> 1, hh = t & 1;
    float s = 0.f;
    for (int c = 0; c < 64; ++c) s += We1[d * 128 + hh * 64 + c] * ae1[hh * 64 + c];
    q[t] = s;
  } else if (t < 9) {
    int d = t - 6;
    q[8 + d] = We2[d * 2 + 0] * ae2[0] + We2[d * 2 + 1] * ae2[1];
  }
  if (t < 128) {
    float s0 = 0.f, s1 = 0.f, d0 = 0.f, d1 = 0.f;
    for (int c = 0; c < 64; ++c) {
      float w0 = W1[t * 128 + c], w1 = W1[t * 128 + 64 + c];
      s0 += w0 * as1[c];      s1 += w1 * as1[64 + c];
      d0 += w0 * ad1[c];      d1 += w1 * ad1[64 + c];
    }
    pq[t] = make_float4(s0, s1, d0, d1);
  }
}

// ---------- MERGED: hist (blocks [0,256)) + layer1 GEMM (blocks [256,256+782)) ----
// Roles are fully independent (disjoint reads/writes); merged grid packs the GPU.
// LDS union: hist cnt (50KB) vs gemm xa+wt (64KB) -> 64KB static.
__global__ __launch_bounds__(512, 4) void k_gh(
    const int* __restrict__ ei, unsigned short* __restrict__ off16,
    unsigned short* __restrict__ rank,
    const float* __restrict__ x, const float* __restrict__ W,
    const float4* __restrict__ pq, unsigned short* __restrict__ h1b,
    float* __restrict__ a1s, float* __restrict__ a1d) {
  __shared__ union SM {
    struct { unsigned short xa[128 * 128]; unsigned short wt[128 * 128]; } g;
    unsigned cnt[HBW];
  } sm;
  int t = threadIdx.x;

  if (blockIdx.x < HIST_BLKS) {
    // ---- hist role (512 threads) ----
    int b = blockIdx.x >> 2;               // edge chunk
    int pass = blockIdx.x & 3;             // node range
    int base = pass * HBIN;
    for (int i = t; i < HBW; i += 512) sm.cnt[i] = 0;
    __syncthreads();
    const int* dsts = &ei[NE + b * EB];
    for (int i = t * 4; i < EB; i += 2048) {
      int4 d = *(const int4*)&dsts[i];
      int dv[4] = {d.x, d.y, d.z, d.w};
#pragma unroll
      for (int j = 0; j < 4; ++j) {
        int rel = dv[j] - base;
        if ((unsigned)rel < (unsigned)HBIN) {
          unsigned sh = (unsigned)(rel & 1) << 4;
          unsigned old = atomicAdd(&sm.cnt[rel >> 1], 1u << sh);
          rank[b * EB + i + j] = (unsigned short)((old >> sh) & 0xffffu);
        }
      }
    }
    __syncthreads();
    unsigned short* dp = &off16[(size_t)b * NN + base];
    for (int i = t; i < HBW; i += 512) *(unsigned*)&dp[i * 2] = sm.cnt[i];
    return;
  }

  // ---- gemm role ----
  unsigned short* xa = sm.g.xa;
  unsigned short* wt = sm.g.wt;
  int row0 = (int)(blockIdx.x - HIST_BLKS) * 128;

  // stage W^T (fp32 -> bf16, transposed, swizzled)
  {
    int kr = t >> 2, n0 = (t & 3) * 32;
    const float* wp = &W[kr * 128 + n0];
    int cb = kr >> 3, klo = kr & 7;
#pragma unroll
    for (int j = 0; j < 8; ++j) {
      float4 v = *(const float4*)&wp[j * 4];
      int n = n0 + j * 4;
      wt[(n + 0) * 128 + ((cb ^ ((n + 0) & 15)) * 8) + klo] = f2b(v.x);
      wt[(n + 1) * 128 + ((cb ^ ((n + 1) & 15)) * 8) + klo] = f2b(v.y);
      wt[(n + 2) * 128 + ((cb ^ ((n + 2) & 15)) * 8) + klo] = f2b(v.z);
      wt[(n + 3) * 128 + ((cb ^ ((n + 3) & 15)) * 8) + klo] = f2b(v.w);
    }
  }
  // stage x tile (fp32 -> bf16, swizzled) + alpha-scalar partial dots on fp32 x
  {
    int lrow = t >> 2, qq = t & 3;
    int grow = row0 + lrow; if (grow >= NN) grow = NN - 1;
    const float* xp = &x[(size_t)grow * 128 + qq * 32];
    const float4* pqp = &pq[qq * 32];
    float ps0 = 0.f, ps1 = 0.f, pd0 = 0.f, pd1 = 0.f;
    int sw = lrow & 15;
#pragma unroll
    for (int j = 0; j < 4; ++j) {
      float4 u = *(const float4*)&xp[j * 8];
      float4 v = *(const float4*)&xp[j * 8 + 4];
      float xs[8] = {u.x, u.y, u.z, u.w, v.x, v.y, v.z, v.w};
      short8 sv;
#pragma unroll
      for (int e = 0; e < 8; ++e) {
        float4 pv = pqp[j * 8 + e];
        ps0 += xs[e] * pv.x; ps1 += xs[e] * pv.y;
        pd0 += xs[e] * pv.z; pd1 += xs[e] * pv.w;
        sv[e] = (short)f2b(xs[e]);
      }
      int c = qq * 4 + j;
      *(short8*)&xa[lrow * 128 + ((c ^ sw) * 8)] = sv;
    }
    ps0 += __shfl_xor(ps0, 1); ps0 += __shfl_xor(ps0, 2);
    ps1 += __shfl_xor(ps1, 1); ps1 += __shfl_xor(ps1, 2);
    pd0 += __shfl_xor(pd0, 1); pd0 += __shfl_xor(pd0, 2);
    pd1 += __shfl_xor(pd1, 1); pd1 += __shfl_xor(pd1, 2);
    if (qq == 0) {
      *(float2*)&a1s[grow * 2] = make_float2(ps0, ps1);
      *(float2*)&a1d[grow * 2] = make_float2(pd0, pd1);
    }
  }
  __syncthreads();

  int lane = t & 63, w = t >> 6;
  int m = lane & 15, quad = lane >> 4;
  int wm = (w & 1) * 64, wn = (w >> 1) * 32;
  f32x4 acc[4][2];
#pragma unroll
  for (int mi = 0; mi < 4; ++mi)
#pragma unroll
    for (int ni = 0; ni < 2; ++ni) acc[mi][ni] = (f32x4)(0.f);

#pragma unroll
  for (int kk = 0; kk < 4; ++kk) {
    int c = kk * 4 + quad;
    int co = (c ^ m) * 8;
    short8 a[4], b[2];
#pragma unroll
    for (int mi = 0; mi < 4; ++mi)
      a[mi] = *(const short8*)&xa[(wm + mi * 16 + m) * 128 + co];
#pragma unroll
    for (int ni = 0; ni < 2; ++ni)
      b[ni] = *(const short8*)&wt[(wn + ni * 16 + m) * 128 + co];
#pragma unroll
    for (int mi = 0; mi < 4; ++mi)
#pragma unroll
      for (int ni = 0; ni < 2; ++ni)
        acc[mi][ni] = __builtin_amdgcn_mfma_f32_16x16x32_bf16(a[mi], b[ni], acc[mi][ni], 0, 0, 0);
  }
#pragma unroll
  for (int mi = 0; mi < 4; ++mi)
#pragma unroll
    for (int r = 0; r < 4; ++r) {
      int grow = row0 + wm + mi * 16 + quad * 4 + r;
      if (grow >= NN) grow = NN - 1;
#pragma unroll
      for (int ni = 0; ni < 2; ++ni)
        h1b[(size_t)grow * 128 + wn + ni * 16 + m] = f2h(acc[mi][ni][r]);
    }
}

// padded segment length: (deg+1) rounded up to multiple of 8
__device__ __forceinline__ int padlen(int d) { return (d + 8) & ~7; }

// ---------- degscan: per-node degree + in-place chunk prefix + per-block sums ----
// 391 blocks x 256 threads, 1 node/thread. bsum[b] = sum of padded lengths of
// nodes [b*256, b*256+256).
__global__ void k_degscan(unsigned short* __restrict__ off16, int* __restrict__ deg,
                          int* __restrict__ bsum) {
  __shared__ int lds[256];
  int t = threadIdx.x;
  int n = blockIdx.x * 256 + t;
  int run = 0;
  if (n < NN) {
    for (int b = 0; b < HB; ++b) {
      size_t idx = (size_t)b * NN + n;
      int c = off16[idx];
      off16[idx] = (unsigned short)run;   // exclusive offset of chunk b within node n
      run += c;
    }
    deg[n] = run;
  }
  lds[t] = (n < NN) ? padlen(run) : 0;
  __syncthreads();
  for (int o = 128; o > 0; o >>= 1) { if (t < o) lds[t] += lds[t + o]; __syncthreads(); }
  if (t == 0) bsum[blockIdx.x] = lds[0];
}

// scan3: rowptr, with the global bsum prefix folded in (scan2 eliminated).
// Block j's base = sum of bsum[0 .. 4j) (block j covers degscan blocks 4j..4j+3).
__global__ void k_scan3(const int* __restrict__ deg, const int* __restrict__ bsum,
                        int* __restrict__ rowptr) {
  __shared__ int lds[256];
  __shared__ int bb;
  int t = threadIdx.x;
  int lim = blockIdx.x * 4;
  int a = 0;
  for (int i = t; i < lim; i += 256) a += bsum[i];
  lds[t] = a; __syncthreads();
  for (int o = 128; o > 0; o >>= 1) { if (t < o) lds[t] += lds[t + o]; __syncthreads(); }
  if (t == 0) bb = lds[0];
  __syncthreads();
  int base = blockIdx.x * 1024 + t * 4;
  int v[4]; int s = 0;
  for (int j = 0; j < 4; ++j) { int i = base + j; v[j] = (i < NN) ? padlen(deg[i]) : 0; s += v[j]; }
  lds[t] = s; __syncthreads();
  for (int o = 1; o < 256; o <<= 1) {
    int u = (t >= o) ? lds[t - o] : 0;
    __syncthreads();
    lds[t] += u;
    __syncthreads();
  }
  int excl = lds[t] - s + bb;
  for (int j = 0; j < 4; ++j) {
    int i = base + j;
    if (i <= NN) rowptr[i] = excl;
    excl += v[j];
  }
}

// ---------- scatter edges into CSR + fill self/pad packets: NO atomics ----------
// Blocks [0, EDGE_BLKS): pos = rowptr[dst]+1+off16[chunk][dst]+rank (reproducible).
// Blocks [EDGE_BLKS, +FILL_BLKS): 1 thread/node writes self-loop (slot 0) + tail pads.
// Slots provably disjoint (self=0, edges=1..deg, pads=deg+1..padlen-1).
__global__ void k_scatter(const int* __restrict__ ei, const float* __restrict__ ef,
                          const float* __restrict__ a1s, const float* __restrict__ a1d,
                          const float* __restrict__ q, const int* __restrict__ rowptr,
                          const int* __restrict__ deg,
                          const unsigned short* __restrict__ rank,
                          const unsigned short* __restrict__ off16,
                          float2* __restrict__ cpk1) {
  int bid = blockIdx.x;
  if (bid < EDGE_BLKS) {
    int t4 = bid * 256 + threadIdx.x;
    if (t4 >= NE / 4) return;
    int e0 = t4 * 4;
    int hb = e0 / EB;                     // all 4 edges in same chunk (EB % 4 == 0)
    const unsigned short* offp = &off16[(size_t)hb * NN];
    int4 ss = *(const int4*)&ei[e0];
    int4 dd = *(const int4*)&ei[NE + e0];
    ushort4 rk = *(const ushort4*)&rank[e0];
    float4 fA = *(const float4*)&ef[e0 * 3];
    float4 fB = *(const float4*)&ef[e0 * 3 + 4];
    float4 fC = *(const float4*)&ef[e0 * 3 + 8];
    float f[4][3] = {{fA.x, fA.y, fA.z}, {fA.w, fB.x, fB.y},
                     {fB.z, fB.w, fC.x}, {fC.y, fC.z, fC.w}};
    int src[4] = {ss.x, ss.y, ss.z, ss.w};
    int dst[4] = {dd.x, dd.y, dd.z, dd.w};
    int rnk[4] = {rk.x, rk.y, rk.z, rk.w};
#pragma unroll
    for (int j = 0; j < 4; ++j) {
      float e0h = f[j][0] * q[0] + f[j][1] * q[2] + f[j][2] * q[4];
      float e1h = f[j][0] * q[1] + f[j][1] * q[3] + f[j][2] * q[5];
      float ez  = f[j][0] * q[8] + f[j][1] * q[9] + f[j][2] * q[10];
      float al0 = a1s[src[j] * 2] + a1d[dst[j] * 2] + e0h;
      float al1 = a1s[src[j] * 2 + 1] + a1d[dst[j] * 2 + 1] + e1h;
      al0 = al0 > 0.f ? al0 : NEG_SLOPE * al0;
      al1 = al1 > 0.f ? al1 : NEG_SLOPE * al1;
      int pos = rowptr[dst[j]] + 1 + (int)offp[dst[j]] + rnk[j];
      cpk1[pos] = make_float2(
          __uint_as_float(pkh2(__expf(al0 - WSHIFT), __expf(al1 - WSHIFT))),
          __uint_as_float(pkSE(src[j], ez)));
    }
  } else {
    int n = (bid - EDGE_BLKS) * 256 + threadIdx.x;
    if (n >= NN) return;
    int s0 = rowptr[n];
    int d = deg[n];
    int pl = padlen(d);
    float2 sv = *(const float2*)&a1s[n * 2];
    float2 dv = *(const float2*)&a1d[n * 2];
    float al0 = sv.x + dv.x;
    float al1 = sv.y + dv.y;
    al0 = al0 > 0.f ? al0 : NEG_SLOPE * al0;
    al1 = al1 > 0.f ? al1 : NEG_SLOPE * al1;
    cpk1[s0] = make_float2(
        __uint_as_float(pkh2(__expf(al0 - WSHIFT), __expf(al1 - WSHIFT))),
        __uint_as_float(pkSE(n, 0.f)));       // self-loop at slot 0, ez = 0
    float2 pad = make_float2(0.f, __uint_as_float(pkSE(n, EZPAD)));
    for (int k = 1 + d; k < pl; ++k) cpk1[s0 + k] = pad;
  }
}

// ---------- layer1 aggregation + bias + ELU + layer2 projection epilogue ----------
// one wave per dst node; 16-lane granules; f16 h1 rows + f16x2 packed weights.
// 8B packets (w01, ez|src) read as paired nt float4 loads; src = .y & 0x1FFFF.
__global__ __launch_bounds__(256) void k_agg1(const unsigned short* __restrict__ h1b,
                                              const int* __restrict__ rowptr,
                                              const float2* __restrict__ cpk1,
                                              const float* __restrict__ b1,
                                              const float* __restrict__ W2,
                                              const float* __restrict__ as2,
                                              const float* __restrict__ ad2,
                                              float4* __restrict__ nd) {
  int n = (int)((blockIdx.x * 256 + threadIdx.x) >> 6);
  int lane = threadIdx.x & 63;
  if (n >= NN) return;
  int s0 = rowptr[n], s1 = rowptr[n + 1];
  int g = lane >> 4;
  int lp = lane & 15;
  int wsel = (lp >= 8) ? HSEL_HI : HSEL_LO;

  float acc[8];
#pragma unroll
  for (int j = 0; j < 8; ++j) acc[j] = 0.f;
  float den = 0.f;

  int i = s0;
  for (; i + 16 <= s1; i += 16) {
    const float4* pp = (const float4*)(cpk1 + i + 4 * g);
    float4 p01 = ntld4(pp);       // (wA, yA, wB, yB)
    float4 p23 = ntld4(pp + 1);   // (wC, yC, wD, yD)
    uint4 vA = *((const uint4*)(h1b + ((size_t)(__float_as_uint(p01.y) & SRCMASK) << 7)) + lp);
    uint4 vB = *((const uint4*)(h1b + ((size_t)(__float_as_uint(p01.w) & SRCMASK) << 7)) + lp);
    uint4 vC = *((const uint4*)(h1b + ((size_t)(__float_as_uint(p23.y) & SRCMASK) << 7)) + lp);
    uint4 vD = *((const uint4*)(h1b + ((size_t)(__float_as_uint(p23.w) & SRCMASK) << 7)) + lp);
    unsigned wAB = permb(__float_as_uint(p01.z), __float_as_uint(p01.x), wsel);
    unsigned wCD = permb(__float_as_uint(p23.z), __float_as_uint(p23.x), wsel);
    den = dot2h(wAB, ONE2, den);
    den = dot2h(wCD, ONE2, den);
    acc[0] = dot2h(permb(vB.x, vA.x, HSEL_LO), wAB, acc[0]);
    acc[1] = dot2h(permb(vB.x, vA.x, HSEL_HI), wAB, acc[1]);
    acc[2] = dot2h(permb(vB.y, vA.y, HSEL_LO), wAB, acc[2]);
    acc[3] = dot2h(permb(vB.y, vA.y, HSEL_HI), wAB, acc[3]);
    acc[4] = dot2h(permb(vB.z, vA.z, HSEL_LO), wAB, acc[4]);
    acc[5] = dot2h(permb(vB.z, vA.z, HSEL_HI), wAB, acc[5]);
    acc[6] = dot2h(permb(vB.w, vA.w, HSEL_LO), wAB, acc[6]);
    acc[7] = dot2h(permb(vB.w, vA.w, HSEL_HI), wAB, acc[7]);
    acc[0] = dot2h(permb(vD.x, vC.x, HSEL_LO), wCD, acc[0]);
    acc[1] = dot2h(permb(vD.x, vC.x, HSEL_HI), wCD, acc[1]);
    acc[2] = dot2h(permb(vD.y, vC.y, HSEL_LO), wCD, acc[2]);
    acc[3] = dot2h(permb(vD.y, vC.y, HSEL_HI), wCD, acc[3]);
    acc[4] = dot2h(permb(vD.z, vC.z, HSEL_LO), wCD, acc[4]);
    acc[5] = dot2h(permb(vD.z, vC.z, HSEL_HI), wCD, acc[5]);
    acc[6] = dot2h(permb(vD.w, vC.w, HSEL_LO), wCD, acc[6]);
    acc[7] = dot2h(permb(vD.w, vC.w, HSEL_HI), wCD, acc[7]);
  }
  if (i < s1) {                       // exactly one 8-edge block
    float4 p = ntld4((const float4*)(cpk1 + i + 2 * g));
    uint4 vA = *((const uint4*)(h1b + ((size_t)(__float_as_uint(p.y) & SRCMASK) << 7)) + lp);
    uint4 vB = *((const uint4*)(h1b + ((size_t)(__float_as_uint(p.w) & SRCMASK) << 7)) + lp);
    unsigned wAB = permb(__float_as_uint(p.z), __float_as_uint(p.x), wsel);
    den = dot2h(wAB, ONE2, den);
    acc[0] = dot2h(permb(vB.x, vA.x, HSEL_LO), wAB, acc[0]);
    acc[1] = dot2h(permb(vB.x, vA.x, HSEL_HI), wAB, acc[1]);
    acc[2] = dot2h(permb(vB.y, vA.y, HSEL_LO), wAB, acc[2]);
    acc[3] = dot2h(permb(vB.y, vA.y, HSEL_HI), wAB, acc[3]);
    acc[4] = dot2h(permb(vB.z, vA.z, HSEL_LO), wAB, acc[4]);
    acc[5] = dot2h(permb(vB.z, vA.z, HSEL_HI), wAB, acc[5]);
    acc[6] = dot2h(permb(vB.w, vA.w, HSEL_LO), wAB, acc[6]);
    acc[7] = dot2h(permb(vB.w, vA.w, HSEL_HI), wAB, acc[7]);
  }
#pragma unroll
  for (int o = 16; o <= 32; o <<= 1) {
    den += __shfl_xor(den, o);
#pragma unroll
    for (int j = 0; j < 8; ++j) acc[j] += __shfl_xor(acc[j], o);
  }
  float4 bA = *(const float4*)&b1[lp * 8];
  float4 bB = *(const float4*)&b1[lp * 8 + 4];
  float bb[8] = {bA.x, bA.y, bA.z, bA.w, bB.x, bB.y, bB.z, bB.w};
  float inv = 1.f / (den + GEPS);
  float r[8];
#pragma unroll
  for (int j = 0; j < 8; ++j) {
    float v = acc[j] * inv + bb[j];
    r[j] = v > 0.f ? v : __expf(v) - 1.f;   // ELU
  }
  float4 wA = *(const float4*)&W2[lp * 16];
  float4 wB = *(const float4*)&W2[lp * 16 + 4];
  float4 wC = *(const float4*)&W2[lp * 16 + 8];
  float4 wD = *(const float4*)&W2[lp * 16 + 12];
  float p20 = r[0] * wA.x + r[1] * wA.z + r[2] * wB.x + r[3] * wB.z
            + r[4] * wC.x + r[5] * wC.z + r[6] * wD.x + r[7] * wD.z;
  float p21 = r[0] * wA.y + r[1] * wA.w + r[2] * wB.y + r[3] * wB.w
            + r[4] * wC.y + r[5] * wC.w + r[6] * wD.y + r[7] * wD.w;
#pragma unroll
  for (int o = 1; o <= 8; o <<= 1) { p20 += __shfl_xor(p20, o); p21 += __shfl_xor(p21, o); }
  if (lane == 0) {
    float4 v;
    v.x = p20; v.y = p21;
    v.z = p20 * as2[0] + p21 * as2[1];
    v.w = p20 * ad2[0] + p21 * ad2[1];
    nd[n] = v;
  }
}

// ---------- layer2 aggregation: 4 nodes/wave (16-lane granules) ----------
// src/ez both decoded from packet .y (nt load). Pads: ez=-60000 -> exp()=0.
__global__ __launch_bounds__(256) void k_agg2(const int* __restrict__ rowptr,
                                              const float2* __restrict__ cpk1,
                                              const float4* __restrict__ nd,
                                              const float* __restrict__ b2,
                                              float* __restrict__ out) {
  int wid = (int)((blockIdx.x * 256 + threadIdx.x) >> 6);
  int lane = threadIdx.x & 63;
  int g = lane >> 4, lp = lane & 15;
  int n = wid * 4 + g;
  if (n >= NN) return;
  int s0 = rowptr[n], s1 = rowptr[n + 1];
  float adn = nd[n].w;
  float den = 0.f, acc0 = 0.f, acc1 = 0.f;
  for (int i = s0 + lp; i < s1; i += 16) {
    float2 pk = ntld2(&cpk1[i]);
    unsigned y = __float_as_uint(pk.y);
    int s = (int)(y & SRCMASK);
    float ezv = unpkEZ(y);
    float4 ns = nd[s];
    float v = ns.z + adn + ezv;
    v = v > 0.f ? v : NEG_SLOPE * v;
    float p = __expf(v);
    den += p;
    acc0 += p * ns.x;
    acc1 += p * ns.y;
  }
#pragma unroll
  for (int o = 1; o <= 8; o <<= 1) {
    den += __shfl_xor(den, o);
    acc0 += __shfl_xor(acc0, o);
    acc1 += __shfl_xor(acc1, o);
  }
  if (lp == 0) {
    float2 r;
    r.x = acc0 / (den + GEPS) + b2[0];
    r.y = acc1 / (den + GEPS) + b2[1];
    *(float2*)&out[n * 2] = r;
  }
}

extern "C" void kernel_launch(void* const* d_in, const int* in_sizes, int n_in,
                              void* d_out, int out_size, void* d_ws, size_t ws_size,
                              hipStream_t stream) {
  (void)in_sizes; (void)n_in; (void)out_size; (void)ws_size;
  const float* x   = (const float*)d_in[0];
  const int*   ei  = (const int*)d_in[1];
  const float* ef  = (const float*)d_in[2];
  const float* W1  = (const float*)d_in[3];
  const float* We1 = (const float*)d_in[4];
  const float* as1 = (const float*)d_in[5];
  const float* ad1 = (const float*)d_in[6];
  const float* ae1 = (const float*)d_in[7];
  const float* b1  = (const float*)d_in[8];
  const float* W2  = (const float*)d_in[9];
  const float* We2 = (const float*)d_in[10];
  const float* as2 = (const float*)d_in[11];
  const float* ad2 = (const float*)d_in[12];
  const float* ae2 = (const float*)d_in[13];
  const float* b2  = (const float*)d_in[14];
  float* out = (float*)d_out;

  char* w = (char*)d_ws;
  auto alloc = [&](size_t bytes) -> char* {
    char* p = w; w += (bytes + 255) & ~(size_t)255; return p;
  };
  unsigned short* h1b = (unsigned short*)alloc((size_t)NN * 128 * 2);  // 25.6 MB (f16)
  float*  a1s    = (float*)alloc((size_t)NN * 2 * 4);
  float*  a1d    = (float*)alloc((size_t)NN * 2 * 4);
  float4* nd     = (float4*)alloc((size_t)NN * 16);
  float*  q      = (float*)alloc(64);
  float4* pq     = (float4*)alloc(128 * 16);
  int*    deg    = (int*)alloc((size_t)NN * 4);
  int*    rowptr = (int*)alloc((size_t)(NN + 1) * 4);
  unsigned short* rank  = (unsigned short*)alloc((size_t)NE * 2);       // 3.2 MB
  unsigned short* off16 = (unsigned short*)alloc((size_t)HB * NN * 2);  // 12.8 MB
  int*    bsum   = (int*)alloc(512 * 4);                                // 391 used
  float2* cpk1   = (float2*)alloc(CAPS * 8);                            // 19.2 MB
  // total ≈ 63 MB (well under round-1's proven 77.6 MB)

  const int NB_SCAN = (NN + 1023) / 1024;                 // 98

  hipLaunchKernelGGL(k_prep, dim3(1), dim3(128), 0, stream,
                     We1, ae1, We2, ae2, W1, as1, ad1, q, pq);
  hipLaunchKernelGGL(k_gh, dim3(HIST_BLKS + GEMM_BLKS), dim3(512), 0, stream,
                     ei, off16, rank, x, W1, pq, h1b, a1s, a1d);
  hipLaunchKernelGGL(k_degscan, dim3(NB_DEG), dim3(256), 0, stream, off16, deg, bsum);
  hipLaunchKernelGGL(k_scan3, dim3(NB_SCAN), dim3(256), 0, stream, deg, bsum, rowptr);
  hipLaunchKernelGGL(k_scatter, dim3(EDGE_BLKS + FILL_BLKS), dim3(256), 0, stream,
                     ei, ef, a1s, a1d, q, rowptr, deg, rank, off16, cpk1);
  hipLaunchKernelGGL(k_agg1, dim3((NN * 64 + 255) / 256), dim3(256), 0, stream,
                     h1b, rowptr, cpk1, b1, W2, as2, ad2, nd);
  hipLaunchKernelGGL(k_agg2, dim3(((NN + 3) / 4 * 64 + 255) / 256), dim3(256), 0, stream,
                     rowptr, cpk1, nd, b2, out);
}